// Round 5
// baseline (2726.321 us; speedup 1.0000x reference)
//
#include <hip/hip_runtime.h>

#define Bsz 2048
#define Ssz 96
#define Fsz 32
#define Hsz 256
#define Osz 6
#define LAsz 32
#define RT 8                  // batch rows per block; grid = 256 = 1 block/CU
#define NSTEP (Ssz + LAsz)
#define NTHR 512              // 8 waves; lane = (j mod 32, q); wave w owns j in [32w,32w+32)
#define XW 320                // xh row: cols [0,32)=x, [32,288)=h, rest pad
#define SQ 72                 // k-quads: 8 from W_ih then 64 from W_hh (contiguous k)

typedef float v2f __attribute__((ext_vector_type(2)));

// packed f32 FMA: acc.lo += a.lo*b.lo, acc.hi += a.hi*b.hi
#define PKFMA(acc, a, b) \
    asm("v_pk_fma_f32 %0, %1, %2, %0" : "+v"(acc) : "v"(a), "v"(b))

__device__ __forceinline__ v2f lo2(float4 v) { v2f r; r.x = v.x; r.y = v.y; return r; }
__device__ __forceinline__ v2f hi2(float4 v) { v2f r; r.x = v.z; r.y = v.w; return r; }

// ---------- accurate f64 exp (|rel err| ~1e-14) ----------
__device__ __forceinline__ double exp_d(double x) {
    x = fmin(fmax(x, -700.0), 700.0);
    const double LOG2E = 1.4426950408889634074;
    const double LN2HI = 6.93147180369123816490e-01;
    const double LN2LO = 1.90821492927058770002e-10;
    double n = __builtin_rint(x * LOG2E);
    double r = fma(-n, LN2HI, x);
    r = fma(-n, LN2LO, r);
    double p = 2.5052108385441718775e-08;
    p = fma(p, r, 2.7557319223985890653e-07);
    p = fma(p, r, 2.7557319223985892511e-06);
    p = fma(p, r, 2.4801587301587301566e-05);
    p = fma(p, r, 1.9841269841269841253e-04);
    p = fma(p, r, 1.3888888888888889419e-03);
    p = fma(p, r, 8.3333333333333332177e-03);
    p = fma(p, r, 4.1666666666666664354e-02);
    p = fma(p, r, 1.6666666666666665741e-01);
    p = fma(p, r, 5.0e-01);
    p = fma(p, r, 1.0);
    p = fma(p, r, 1.0);
    long long bits = (long long)(1023 + (int)n) << 52;
    return p * __longlong_as_double(bits);
}

__device__ __forceinline__ double recip_d(double y) {
    double r = (double)(1.0f / (float)y);
    r = fma(fma(-y, r, 1.0), r, r);
    r = fma(fma(-y, r, 1.0), r, r);
    r = fma(fma(-y, r, 1.0), r, r);
    return r;
}
__device__ __forceinline__ double sigmoid_d(double x) { return recip_d(1.0 + exp_d(-x)); }
__device__ __forceinline__ double tanh_d(double x) {
    double ax = fabs(x);
    double t = exp_d(-2.0 * ax);
    double r = (1.0 - t) * recip_d(1.0 + t);
    return x >= 0.0 ? r : -r;
}

// ---------- pre-pass: unified k-major float4 weight tile ----------
// wxT[s*1024 + g*256 + j] = k-quad s of gate-row (g*256+j); s<8 from W_ih, else W_hh
__global__ void transpose_w(const float* __restrict__ W_ih,
                            const float* __restrict__ W_hh,
                            float4* __restrict__ wxT)
{
    int i = blockIdx.x * 256 + threadIdx.x;   // 1024 * 72 total
    if (i >= 1024 * SQ) return;
    int gr = i / SQ, s = i - gr * SQ;
    const float* p = (s < 8) ? (W_ih + (size_t)gr * Fsz + s * 4)
                             : (W_hh + (size_t)gr * Hsz + (s - 8) * 4);
    wxT[(size_t)s * 1024 + gr] = make_float4(p[0], p[1], p[2], p[3]);
}

// 8 ascending-k packed FMAs (4 insts) for one gate acc; h pairs in scope
#define DOTPK(acc, WA, WB)        \
    PKFMA(acc, lo2(WA), h0l);     \
    PKFMA(acc, hi2(WA), h0h);     \
    PKFMA(acc, lo2(WB), h1l);     \
    PKFMA(acc, hi2(WB), h1h);

// one 8-k sub-block for all 4 gates x 8 rows, reading from hp (lane's col base)
#define COMPUTE(WA, WB, hp)                                             \
    do {                                                                \
        _Pragma("unroll")                                               \
        for (int rr = 0; rr < 4; ++rr) {                                \
            float4 H0 = *(const float4*)((hp) + rr * XW);               \
            float4 H1 = *(const float4*)((hp) + rr * XW + 4);           \
            v2f h0l = lo2(H0), h0h = hi2(H0), h1l = lo2(H1), h1h = hi2(H1); \
            DOTPK(accA[0][rr], WA[0], WB[0]);                           \
            DOTPK(accA[1][rr], WA[1], WB[1]);                           \
            DOTPK(accA[2][rr], WA[2], WB[2]);                           \
            DOTPK(accA[3][rr], WA[3], WB[3]);                           \
        }                                                               \
        _Pragma("unroll")                                               \
        for (int rr = 0; rr < 4; ++rr) {                                \
            float4 H0 = *(const float4*)((hp) + (4 + rr) * XW);         \
            float4 H1 = *(const float4*)((hp) + (4 + rr) * XW + 4);     \
            v2f h0l = lo2(H0), h0h = hi2(H0), h1l = lo2(H1), h1h = hi2(H1); \
            DOTPK(accB[0][rr], WA[0], WB[0]);                           \
            DOTPK(accB[1][rr], WA[1], WB[1]);                           \
            DOTPK(accB[2][rr], WA[2], WB[2]);                           \
            DOTPK(accB[3][rr], WA[3], WB[3]);                           \
        }                                                               \
    } while (0)

__global__ __launch_bounds__(NTHR, 2) void lstm_persist(
    const float* __restrict__ x,
    const float4* __restrict__ wxT,
    const float* __restrict__ b_ih, const float* __restrict__ b_hh,
    const float* __restrict__ W_fc, const float* __restrict__ b_fc,
    float* __restrict__ out)
{
    __shared__ __align__(16) float xh[2][RT][XW];       // 20 KB, step-parity dbuf
    __shared__ double o_lds[RT][Osz];
    __shared__ float  wfc_lds[Osz * Hsz];               // 6 KB

    const int tid  = threadIdx.x;
    const int row0 = blockIdx.x * RT;
    const int w    = tid >> 6;                           // wave id; owns j-range
    const int l    = tid & 63;
    const int j    = (w << 5) + (l & 31);                // gate-channel owned
    const int q    = l >> 5;                             // k-half (LANE property)

    for (int i = tid; i < 2 * RT * XW; i += NTHR) ((float*)xh)[i] = 0.0f;
    for (int i = tid; i < Osz * Hsz; i += NTHR) wfc_lds[i] = W_fc[i];

    const double bias0 = (double)b_ih[0 * Hsz + j] + (double)b_hh[0 * Hsz + j];
    const double bias1 = (double)b_ih[1 * Hsz + j] + (double)b_hh[1 * Hsz + j];
    const double bias2 = (double)b_ih[2 * Hsz + j] + (double)b_hh[2 * Hsz + j];
    const double bias3 = (double)b_ih[3 * Hsz + j] + (double)b_hh[3 * Hsz + j];

    double c_reg[4];                 // c for rows q*4 + 0..3 of channel j
    #pragma unroll
    for (int r = 0; r < 4; ++r) c_reg[r] = 0.0;

    // per-lane weight base: k-half q starts at s-quad q*36; column j
    const float4* wp_base = wxT + (size_t)(q * 36) * 1024 + j;
    const int rbase = q * 4;                             // rows this lane finalizes

    __syncthreads();

    for (int t = 0; t < NSTEP; ++t) {
        const int p = t & 1;
        // ---- stage x[:, t (or t-Ssz), :] into xh[p] cols [0,32); fuse o feedback ----
        if (tid < RT * Fsz) {
            int r = tid >> 5, f = tid & 31;
            int ts = (t < Ssz) ? t : (t - Ssz);
            float v;
            if (t >= Ssz && f < Osz) v = (float)o_lds[r][f];
            else v = x[((size_t)(row0 + r) * Ssz + ts) * Fsz + f];
            xh[p][r][f] = v;
        }
        __syncthreads();                                 // A: xh[p] complete (x + h)

        // packed f32 accumulators (.x/.y = interleaved k-partials)
        v2f accA[4][4], accB[4][4];
        #pragma unroll
        for (int g = 0; g < 4; ++g)
            #pragma unroll
            for (int rr = 0; rr < 4; ++rr) {
                accA[g][rr].x = 0.0f; accA[g][rr].y = 0.0f;
                accB[g][rr].x = 0.0f; accB[g][rr].y = 0.0f;
            }

        // lane's contiguous col range: q0 -> [0,144) (x + h[0:112)), q1 -> [144,288)
        const float* hb = &xh[p][0][q * 144];

        // ---- software-pipelined dot loop: 18 iters in pairs, weight dbuf ----
        float4 wA0[4], wB0[4], wA1[4], wB1[4];
        #pragma unroll
        for (int g = 0; g < 4; ++g) {
            wA0[g] = wp_base[(g << 8)];
            wB0[g] = wp_base[1024 + (g << 8)];
        }
        const float4* wp = wp_base + 2048;               // s = base+2 (iter 1)
        #pragma unroll 1
        for (int it = 0; it < 18; it += 2) {
            #pragma unroll
            for (int g = 0; g < 4; ++g) {                // prefetch iter it+1
                wA1[g] = wp[(g << 8)];
                wB1[g] = wp[1024 + (g << 8)];
            }
            wp += 2048;
            COMPUTE(wA0, wB0, hb + 8 * it);
            const float4* wp2 = (it < 16) ? wp : wp_base; // guard last prefetch
            #pragma unroll
            for (int g = 0; g < 4; ++g) {                // prefetch iter it+2
                wA0[g] = wp2[(g << 8)];
                wB0[g] = wp2[1024 + (g << 8)];
            }
            wp += 2048;
            COMPUTE(wA1, wB1, hb + 8 * (it + 1));
        }

        // ---- merge pairs; register exchange with partner lane (l^32) ----
        float pA[4][4], pB[4][4], rc[4][4];
        #pragma unroll
        for (int g = 0; g < 4; ++g)
            #pragma unroll
            for (int rr = 0; rr < 4; ++rr) {
                pA[g][rr] = accA[g][rr].x + accA[g][rr].y;   // rows 0-3 partial
                pB[g][rr] = accB[g][rr].x + accB[g][rr].y;   // rows 4-7 partial
            }
        #pragma unroll
        for (int g = 0; g < 4; ++g)
            #pragma unroll
            for (int rr = 0; rr < 4; ++rr) {
                float send = q ? pA[g][rr] : pB[g][rr];      // what partner finalizes
                rc[g][rr] = __shfl_xor(send, 32, 64);        // partner's half for my rows
            }

        // ---- combine (f64) + f64 activations; h -> xh[p^1] (f32); c in regs ----
        #pragma unroll
        for (int rr = 0; rr < 4; ++rr) {
            float o0 = q ? pB[0][rr] : pA[0][rr];
            float o1 = q ? pB[1][rr] : pA[1][rr];
            float o2 = q ? pB[2][rr] : pA[2][rr];
            float o3 = q ? pB[3][rr] : pA[3][rr];
            double t0 = bias0 + (double)o0 + (double)rc[0][rr];
            double t1 = bias1 + (double)o1 + (double)rc[1][rr];
            double t2 = bias2 + (double)o2 + (double)rc[2][rr];
            double t3 = bias3 + (double)o3 + (double)rc[3][rr];
            double si = sigmoid_d(t0);
            double sf = sigmoid_d(t1);
            double tg = tanh_d(t2);
            double so = sigmoid_d(t3);
            double cn = fma(sf, c_reg[rr], si * tg);
            c_reg[rr] = cn;
            xh[p ^ 1][rbase + rr][32 + j] = (float)(so * tanh_d(cn));
        }

        // ---- readout: wave w owns row w (8 waves, 8 rows) ----
        if (t >= Ssz - 1) {
            __syncthreads();                              // C: h(t) complete in xh[p^1]
            double a0 = 0.0, a1 = 0.0, a2 = 0.0, a3 = 0.0, a4 = 0.0, a5 = 0.0;
            #pragma unroll
            for (int m = 0; m < 4; ++m) {
                int k = l + 64 * m;
                float hv = xh[p ^ 1][w][32 + k];
                bool b = hv > 0.0f;
                a0 += b ? (double)wfc_lds[0 * Hsz + k] : 0.0;
                a1 += b ? (double)wfc_lds[1 * Hsz + k] : 0.0;
                a2 += b ? (double)wfc_lds[2 * Hsz + k] : 0.0;
                a3 += b ? (double)wfc_lds[3 * Hsz + k] : 0.0;
                a4 += b ? (double)wfc_lds[4 * Hsz + k] : 0.0;
                a5 += b ? (double)wfc_lds[5 * Hsz + k] : 0.0;
            }
            #pragma unroll
            for (int off = 32; off >= 1; off >>= 1) {
                a0 += __shfl_down(a0, off, 64);
                a1 += __shfl_down(a1, off, 64);
                a2 += __shfl_down(a2, off, 64);
                a3 += __shfl_down(a3, off, 64);
                a4 += __shfl_down(a4, off, 64);
                a5 += __shfl_down(a5, off, 64);
            }
            if (l == 0) {
                size_t base = ((size_t)(row0 + w) * (LAsz + 1) + (t - (Ssz - 1))) * Osz;
                double o;
                o = (double)b_fc[0] + a0; o_lds[w][0] = o; out[base + 0] = (float)o;
                o = (double)b_fc[1] + a1; o_lds[w][1] = o; out[base + 1] = (float)o;
                o = (double)b_fc[2] + a2; o_lds[w][2] = o; out[base + 2] = (float)o;
                o = (double)b_fc[3] + a3; o_lds[w][3] = o; out[base + 3] = (float)o;
                o = (double)b_fc[4] + a4; o_lds[w][4] = o; out[base + 4] = (float)o;
                o = (double)b_fc[5] + a5; o_lds[w][5] = o; out[base + 5] = (float)o;
            }
            __syncthreads();                              // D: o_lds published
        }
        // non-readout steps: barrier A(t+1) orders h/x writes vs reads (parity dbuf)
    }
}

extern "C" void kernel_launch(void* const* d_in, const int* in_sizes, int n_in,
                              void* d_out, int out_size, void* d_ws, size_t ws_size,
                              hipStream_t stream)
{
    const float* x    = (const float*)d_in[0];
    const float* W_ih = (const float*)d_in[1];
    const float* W_hh = (const float*)d_in[2];
    const float* b_ih = (const float*)d_in[3];
    const float* b_hh = (const float*)d_in[4];
    const float* W_fc = (const float*)d_in[5];
    const float* b_fc = (const float*)d_in[6];
    float* out = (float*)d_out;

    float4* wxT = (float4*)d_ws;                  // 72*1024 float4 = 1.125 MB

    transpose_w<<<dim3((1024 * SQ + 255) / 256), dim3(256), 0, stream>>>(
        W_ih, W_hh, wxT);

    lstm_persist<<<dim3(Bsz / RT), dim3(NTHR), 0, stream>>>(
        x, wxT, b_ih, b_hh, W_fc, b_fc, out);
}